// Round 3
// baseline (1083.935 us; speedup 1.0000x reference)
//
#include <hip/hip_runtime.h>
#include <hip/hip_bf16.h>
#include <stdint.h>

// Problem constants (fixed by reference)
#define BATCH 16
#define NPTS  8192
#define NCH   6
#define NGRP  512   // NUM_GROUPS (FPS samples)
#define GSZ   32    // GROUP_SIZE (kNN)

#define FPS_T   512               // threads per fps block
#define FPS_PPT (NPTS / FPS_T)    // 16 points per thread
#define FPS_W   (FPS_T / 64)      // 8 waves

// ---------------------------------------------------------------------------
// Kernel 1: farthest point sampling. One block per batch (16 CUs active).
// Two-phase argmax per step (f32 value max, then index-min among matches)
// replaces the round-2 u64-key machinery: inner loop is pure f32 (10 ops/pt),
// phase B runs on ~1 wave. Winner publishes the selected point's coords from
// REGISTERS to LDS -> no dependent global reload of P[last].
//
// Numerics (bit-identical to numpy reference, validated round 2):
//   d = (dx*dx + dy*dy) + dz*dz, fp contract off, fminf running min.
//   max is rounding-free, so value-max-then-first-index == np.argmax
//   (first index attaining max == global min index among md[i]==vmax).
// ---------------------------------------------------------------------------
__global__ __launch_bounds__(FPS_T) void fps_kernel(
    const float* __restrict__ points, float* __restrict__ centers) {
#pragma clang fp contract(off)
  const int b    = blockIdx.x;
  const int tid  = threadIdx.x;
  const int lane = tid & 63;
  const int wave = tid >> 6;
  const float* P = points + (size_t)b * NPTS * NCH;
  float* C = centers + (size_t)b * NGRP * 3;

  float px[FPS_PPT], py[FPS_PPT], pz[FPS_PPT], md[FPS_PPT];
#pragma unroll
  for (int j = 0; j < FPS_PPT; ++j) {
    const int i = j * FPS_T + tid;
    px[j] = P[i * 6 + 0];
    py[j] = P[i * 6 + 1];
    pz[j] = P[i * 6 + 2];
    md[j] = __builtin_inff();
  }

  __shared__ float    wval[FPS_W];            // per-wave max value
  __shared__ unsigned wkey[FPS_W];            // (cand<<3)|wave, 0xFFFFFFFF if none
  __shared__ float    wx[FPS_W], wy[FPS_W], wz[FPS_W];  // winner coords

  if (tid == 0) {  // start point = index 0 (owned by tid 0, j 0)
    C[0] = px[0]; C[1] = py[0]; C[2] = pz[0];
    wx[0] = px[0]; wy[0] = py[0]; wz[0] = pz[0];
  }
  __syncthreads();

  unsigned q = 0;  // LDS slot holding the current center's coords
  for (int k = 1; k < NGRP; ++k) {
    const float lx = wx[q], ly = wy[q], lz = wz[q];  // LDS broadcast read

    // ---- phase A: update min-dist, find block max value ----
    float bestv = -__builtin_inff();
#pragma unroll
    for (int j = 0; j < FPS_PPT; ++j) {
      const float dx = px[j] - lx;
      const float dy = py[j] - ly;
      const float dz = pz[j] - lz;
      const float d  = (dx * dx + dy * dy) + dz * dz;  // ref op order, no fma
      md[j] = fminf(md[j], d);
      bestv = fmaxf(bestv, md[j]);
    }
    float wv = bestv;
#pragma unroll
    for (int off = 32; off >= 1; off >>= 1)
      wv = fmaxf(wv, __shfl_xor(wv, off));   // all lanes end with wave max
    if (lane == 0) wval[wave] = wv;
    __syncthreads();  // B1
    float vmax = wval[0];
#pragma unroll
    for (int w2 = 1; w2 < FPS_W; ++w2) vmax = fmaxf(vmax, wval[w2]);

    // ---- phase B: first index attaining vmax (only matching waves work) ----
    if (wv == vmax) {  // wave-uniform
      unsigned cand = 0xFFFFFFFFu;
#pragma unroll
      for (int j = 0; j < FPS_PPT; ++j) {
        const unsigned idx =
            (md[j] == vmax) ? (unsigned)(j * FPS_T + tid) : 0xFFFFFFFFu;
        cand = cand < idx ? cand : idx;      // min idx == first match
      }
      unsigned wc = cand;
#pragma unroll
      for (int off = 32; off >= 1; off >>= 1) {
        const unsigned o = __shfl_xor(wc, off);
        wc = wc < o ? wc : o;
      }
      if (cand == wc) {  // unique owner lane (indices distinct per lane)
        const int cj = (int)(wc >> 9);       // idx = j*512 + tid -> j = idx>>9
        float fx = 0.f, fy = 0.f, fz = 0.f;  // static-indexed select (no spill)
#pragma unroll
        for (int j = 0; j < FPS_PPT; ++j)
          if (cj == j) { fx = px[j]; fy = py[j]; fz = pz[j]; }
        wkey[wave] = (wc << 3) | (unsigned)wave;
        wx[wave] = fx; wy[wave] = fy; wz[wave] = fz;
      }
    } else if (lane == 0) {
      wkey[wave] = 0xFFFFFFFFu;
    }
    __syncthreads();  // B2

    unsigned kmin = wkey[0];
#pragma unroll
    for (int w2 = 1; w2 < FPS_W; ++w2) {
      const unsigned o = wkey[w2];
      kmin = kmin < o ? kmin : o;
    }
    q = kmin & 7u;  // slot of global winner (min key == min global index)
    if (tid == 0) { C[k*3+0] = wx[q]; C[k*3+1] = wy[q]; C[k*3+2] = wz[q]; }
  }
}

// ---------------------------------------------------------------------------
// Kernel 2: 32-NN per (batch, group) + gather + center-relative output.
// (unchanged from round 2 — validated bit-exact; optimize next round)
// ---------------------------------------------------------------------------
__global__ __launch_bounds__(256) void knn_kernel(
    const float* __restrict__ points, const float* __restrict__ centers,
    float* __restrict__ grouped) {
#pragma clang fp contract(off)
  const int g    = blockIdx.x;
  const int b    = blockIdx.y;
  const int tid  = threadIdx.x;
  const int lane = tid & 63;
  const int wave = tid >> 6;
  const float* P   = points + (size_t)b * NPTS * NCH;
  const float* cen = centers + ((size_t)b * NGRP + g) * 3;
  const float cx = cen[0], cy = cen[1], cz = cen[2];
  const float cc = (cx * cx + cy * cy) + cz * cz;

  unsigned long long keys[32];
  for (int j = 0; j < 32; ++j) {
    const int i = j * 256 + tid;
    const float x = P[i * 6 + 0];
    const float y = P[i * 6 + 1];
    const float z = P[i * 6 + 2];
    const float xx  = (x * x + y * y) + z * z;
    const float dot = fmaf(cz, z, fmaf(cy, y, cx * x));  // einsum fma chain
    const float d2  = (cc - 2.0f * dot) + xx;
    unsigned u = __float_as_uint(d2);
    u = (u & 0x80000000u) ? ~u : (u | 0x80000000u);  // sortable map (d2 can be <0)
    keys[j] = ((unsigned long long)u << 32) | (unsigned long long)(unsigned)i;
  }
  unsigned long long lmin = keys[0];
  for (int j = 1; j < 32; ++j) lmin = lmin < keys[j] ? lmin : keys[j];

  __shared__ unsigned long long wred[2][4];
  __shared__ int knn_sh[GSZ];

  for (int j = 0; j < GSZ; ++j) {
    unsigned long long v = lmin;
    for (int off = 32; off >= 1; off >>= 1) {
      const unsigned long long o = __shfl_down(v, off);
      v = v < o ? v : o;
    }
    if (lane == 0) wred[j & 1][wave] = v;
    __syncthreads();
    unsigned long long w = wred[j & 1][0];
    for (int q2 = 1; q2 < 4; ++q2) {
      const unsigned long long o = wred[j & 1][q2];
      w = w < o ? w : o;
    }
    const int widx = (int)(unsigned)(w & 0xFFFFFFFFull);
    if (tid == (widx & 255)) {  // owner removes the winner, rebuilds local min
      for (int s = 0; s < 32; ++s)
        if ((unsigned)(keys[s] & 0xFFFFFFFFull) == (unsigned)widx)
          keys[s] = ~0ull;
      lmin = keys[0];
      for (int s = 1; s < 32; ++s) lmin = lmin < keys[s] ? lmin : keys[s];
    }
    if (tid == 0) knn_sh[j] = widx;
  }
  __syncthreads();

  // gather + center-relative xyz; 192 output floats per group
  float* outg = grouped + ((size_t)b * NGRP + g) * GSZ * NCH;
  for (int t = tid; t < GSZ * NCH; t += 256) {
    const int n = t / 6, c = t % 6;
    const int idx = knn_sh[n];
    float v = P[idx * 6 + c];
    if (c < 3) v = v - cen[c];  // grouped[...,:3] - centers, exact ref subtract
    outg[t] = v;
  }
}

extern "C" void kernel_launch(void* const* d_in, const int* in_sizes, int n_in,
                              void* d_out, int out_size, void* d_ws, size_t ws_size,
                              hipStream_t stream) {
  const float* points = (const float*)d_in[0];
  float* out = (float*)d_out;
  float* grouped = out;                                        // [16,512,32,6]
  float* centers = out + (size_t)BATCH * NGRP * GSZ * NCH;     // [16,512,3]

  fps_kernel<<<BATCH, FPS_T, 0, stream>>>(points, centers);
  knn_kernel<<<dim3(NGRP, BATCH), 256, 0, stream>>>(points, centers, grouped);
}

// Round 4
// 968.046 us; speedup vs baseline: 1.1197x; 1.1197x over previous
//
#include <hip/hip_runtime.h>
#include <hip/hip_bf16.h>
#include <stdint.h>

// Problem constants (fixed by reference)
#define BATCH 16
#define NPTS  8192
#define NCH   6
#define NGRP  512   // NUM_GROUPS (FPS samples)
#define GSZ   32    // GROUP_SIZE (kNN)

#define FPS_T   1024              // threads per fps block (16 waves, 4/SIMD)
#define FPS_PPT (NPTS / FPS_T)    // 8 points per thread
#define FPS_W   (FPS_T / 64)      // 16 waves

// ---------------------------------------------------------------------------
// Kernel 1: farthest point sampling. One block per batch (16 CUs active).
// Round-4 structure: ONE barrier per step.
//   inner loop: pure f32, 10 ops/pt (bit-exact ref order, contract off)
//   per-thread: first-index-at-max via descending-j overwrite (inv = ~idx)
//   wave: single u64 (value<<32 | inv) max butterfly -> leader slot
//   barrier; lane-parallel 16-slot reduce (lane&15 read + 4-stage butterfly)
//   next center coords come from an LDS cache of all point xyz (96 KiB),
//   3 same-address broadcast ds_reads -- no owner-publish, no 2nd barrier.
// Tie-break: larger inv == smaller idx == np.argmax first index (validated
// bit-exact in round 2 with the equivalent 0xFFFFFFFF-idx form).
// ---------------------------------------------------------------------------
__global__ __launch_bounds__(FPS_T) void fps_kernel(
    const float* __restrict__ points, float* __restrict__ centers) {
#pragma clang fp contract(off)
  const int b    = blockIdx.x;
  const int tid  = threadIdx.x;
  const int lane = tid & 63;
  const int wave = tid >> 6;
  const float* P = points + (size_t)b * NPTS * NCH;
  float* C = centers + (size_t)b * NGRP * 3;

  __shared__ float cache[NPTS * 3];                 // xyz cache, 96 KiB
  __shared__ unsigned long long wslot[FPS_W];       // per-wave winner keys

  float px[FPS_PPT], py[FPS_PPT], pz[FPS_PPT], md[FPS_PPT];
#pragma unroll
  for (int j = 0; j < FPS_PPT; ++j) {
    const int i = j * FPS_T + tid;
    px[j] = P[i * 6 + 0];
    py[j] = P[i * 6 + 1];
    pz[j] = P[i * 6 + 2];
    cache[i * 3 + 0] = px[j];
    cache[i * 3 + 1] = py[j];
    cache[i * 3 + 2] = pz[j];
    md[j] = __builtin_inff();
  }
  if (tid == 0) {  // start point = index 0 (tid 0 owns it at j=0)
    C[0] = px[0]; C[1] = py[0]; C[2] = pz[0];
  }
  __syncthreads();  // cache ready

  unsigned widx = 0;  // current center's point index (block-uniform)
  for (int k = 1; k < NGRP; ++k) {
    // broadcast read of current center from LDS cache (same-addr = free)
    const float lx = cache[widx * 3 + 0];
    const float ly = cache[widx * 3 + 1];
    const float lz = cache[widx * 3 + 2];

    // ---- inner: update min-dist, per-thread max (bit-exact ref order) ----
    float bestv = -__builtin_inff();
#pragma unroll
    for (int j = 0; j < FPS_PPT; ++j) {
      const float dx = px[j] - lx;
      const float dy = py[j] - ly;
      const float dz = pz[j] - lz;
      const float d  = (dx * dx + dy * dy) + dz * dz;  // ref op order, no fma
      md[j] = fminf(md[j], d);
      bestv = fmaxf(bestv, md[j]);
    }
    // first index attaining bestv: inv = ~idx decreases with j, so a
    // descending-j overwrite ends at the first (lowest-idx) match.
    unsigned invbest = 0;
#pragma unroll
    for (int j = FPS_PPT - 1; j >= 0; --j) {
      const unsigned inv = ~(unsigned)(j * FPS_T + tid);
      invbest = (md[j] == bestv) ? inv : invbest;
    }
    unsigned long long key =
        ((unsigned long long)__float_as_uint(bestv) << 32) | invbest;

    // ---- wave u64 max butterfly ----
#pragma unroll
    for (int off = 32; off >= 1; off >>= 1) {
      const unsigned long long o = __shfl_xor(key, off);
      key = key > o ? key : o;
    }
    if (lane == 0) wslot[wave] = key;
    __syncthreads();  // the ONLY barrier per step

    // ---- lane-parallel 16-slot reduce (all waves redundantly) ----
    unsigned long long kk = wslot[lane & 15];  // 16 u64 = 32 banks, no conflict
#pragma unroll
    for (int off = 8; off >= 1; off >>= 1) {
      const unsigned long long o = __shfl_xor(kk, off);
      kk = kk > o ? kk : o;
    }
    widx = ~(unsigned)(kk & 0xFFFFFFFFull);

    if (tid == 0) {  // write selected center (3 LDS reads, off critical path)
      C[k * 3 + 0] = cache[widx * 3 + 0];
      C[k * 3 + 1] = cache[widx * 3 + 1];
      C[k * 3 + 2] = cache[widx * 3 + 2];
    }
  }
}

// ---------------------------------------------------------------------------
// Kernel 2: 32-NN per (batch, group) + gather + center-relative output.
// (unchanged from round 2 — validated bit-exact; optimize next round)
// ---------------------------------------------------------------------------
__global__ __launch_bounds__(256) void knn_kernel(
    const float* __restrict__ points, const float* __restrict__ centers,
    float* __restrict__ grouped) {
#pragma clang fp contract(off)
  const int g    = blockIdx.x;
  const int b    = blockIdx.y;
  const int tid  = threadIdx.x;
  const int lane = tid & 63;
  const int wave = tid >> 6;
  const float* P   = points + (size_t)b * NPTS * NCH;
  const float* cen = centers + ((size_t)b * NGRP + g) * 3;
  const float cx = cen[0], cy = cen[1], cz = cen[2];
  const float cc = (cx * cx + cy * cy) + cz * cz;

  unsigned long long keys[32];
  for (int j = 0; j < 32; ++j) {
    const int i = j * 256 + tid;
    const float x = P[i * 6 + 0];
    const float y = P[i * 6 + 1];
    const float z = P[i * 6 + 2];
    const float xx  = (x * x + y * y) + z * z;
    const float dot = fmaf(cz, z, fmaf(cy, y, cx * x));  // einsum fma chain
    const float d2  = (cc - 2.0f * dot) + xx;
    unsigned u = __float_as_uint(d2);
    u = (u & 0x80000000u) ? ~u : (u | 0x80000000u);  // sortable map (d2 can be <0)
    keys[j] = ((unsigned long long)u << 32) | (unsigned long long)(unsigned)i;
  }
  unsigned long long lmin = keys[0];
  for (int j = 1; j < 32; ++j) lmin = lmin < keys[j] ? lmin : keys[j];

  __shared__ unsigned long long wred[2][4];
  __shared__ int knn_sh[GSZ];

  for (int j = 0; j < GSZ; ++j) {
    unsigned long long v = lmin;
    for (int off = 32; off >= 1; off >>= 1) {
      const unsigned long long o = __shfl_down(v, off);
      v = v < o ? v : o;
    }
    if (lane == 0) wred[j & 1][wave] = v;
    __syncthreads();
    unsigned long long w = wred[j & 1][0];
    for (int q2 = 1; q2 < 4; ++q2) {
      const unsigned long long o = wred[j & 1][q2];
      w = w < o ? w : o;
    }
    const int widx = (int)(unsigned)(w & 0xFFFFFFFFull);
    if (tid == (widx & 255)) {  // owner removes the winner, rebuilds local min
      for (int s = 0; s < 32; ++s)
        if ((unsigned)(keys[s] & 0xFFFFFFFFull) == (unsigned)widx)
          keys[s] = ~0ull;
      lmin = keys[0];
      for (int s = 1; s < 32; ++s) lmin = lmin < keys[s] ? lmin : keys[s];
    }
    if (tid == 0) knn_sh[j] = widx;
  }
  __syncthreads();

  // gather + center-relative xyz; 192 output floats per group
  float* outg = grouped + ((size_t)b * NGRP + g) * GSZ * NCH;
  for (int t = tid; t < GSZ * NCH; t += 256) {
    const int n = t / 6, c = t % 6;
    const int idx = knn_sh[n];
    float v = P[idx * 6 + c];
    if (c < 3) v = v - cen[c];  // grouped[...,:3] - centers, exact ref subtract
    outg[t] = v;
  }
}

extern "C" void kernel_launch(void* const* d_in, const int* in_sizes, int n_in,
                              void* d_out, int out_size, void* d_ws, size_t ws_size,
                              hipStream_t stream) {
  const float* points = (const float*)d_in[0];
  float* out = (float*)d_out;
  float* grouped = out;                                        // [16,512,32,6]
  float* centers = out + (size_t)BATCH * NGRP * GSZ * NCH;     // [16,512,3]

  fps_kernel<<<BATCH, FPS_T, 0, stream>>>(points, centers);
  knn_kernel<<<dim3(NGRP, BATCH), 256, 0, stream>>>(points, centers, grouped);
}